// Round 12
// baseline (250.460 us; speedup 1.0000x reference)
//
#include <hip/hip_runtime.h>
#include <hip/hip_bf16.h>
#include <hip/hip_fp16.h>

// GCN2: 3x GCNConv(relu,relu,none) + global_mean_pool + linear head.
// R28: single-pass adjacency build — fixed-capacity adj[node][64] (ushort,
// 128B/row) built directly via deg-atomics (slot<64 hard guard, same drop
// semantics as old cap guard; balls-in-bins max deg ~38 << 64). Deletes
// bents round-trip + build's count/scan/LDS-scatter + csr16 write; build2
// is a trivial dinv/x16h/gcnt pass. Gathers: beg=node*64, no deg>64
// fallback; self-loop = one predicated MIXFMA of own row (grp==0).
// agg16 reverted to R25 form (R27 packed-uint was neutral-negative).
// R25: pool LDS per-graph partials. R24: divergent-barrier fix.
// R22: fp16 y-dot (WsT + v_dot2_f32_f16). R21: 1024-thread agg blocks.
// R20: uniform-exec remainders. R19: register CSR indices + shfl.
// R18: v_fma_mix_f32 gathers. R17: fused y into agg128h.

#define HIDDEN 128
#define F_IN 11
#define NCLS 19
#define EPB 4096
#define CAPA 64   // adjacency capacity per node (128B row)
#define WST 136   // WsT row stride in halves (16B-aligned rows, low bank conflict)

typedef _Float16 half8 __attribute__((ext_vector_type(8)));
typedef _Float16 half2v __attribute__((ext_vector_type(2)));
typedef float floatx4 __attribute__((ext_vector_type(4)));

// acc.{x,y,z,w} += fp16{lo(UX),hi(UX),lo(UY),hi(UY)} * DV   (one inst each)
#define MIXFMA4(A, UX, UY, DV) \
    asm("v_fma_mix_f32 %0, %4, %5, %0 op_sel_hi:[1,0,0]\n\t" \
        "v_fma_mix_f32 %1, %4, %5, %1 op_sel:[1,0,0] op_sel_hi:[1,0,0]\n\t" \
        "v_fma_mix_f32 %2, %6, %5, %2 op_sel_hi:[1,0,0]\n\t" \
        "v_fma_mix_f32 %3, %6, %5, %3 op_sel:[1,0,0] op_sel_hi:[1,0,0]" \
        : "+v"(A.x), "+v"(A.y), "+v"(A.z), "+v"(A.w) \
        : "v"(UX), "v"(DV), "v"(UY))

#define MIXFMA2(AX, AY, UU, DV) \
    asm("v_fma_mix_f32 %0, %2, %3, %0 op_sel_hi:[1,0,0]\n\t" \
        "v_fma_mix_f32 %1, %2, %3, %1 op_sel:[1,0,0] op_sel_hi:[1,0,0]" \
        : "+v"(AX), "+v"(AY) : "v"(UU), "v"(DV))

#define MIXFMA1(AX, HU, DV) \
    asm("v_fma_mix_f32 %0, %1, %2, %0 op_sel_hi:[1,0,0]" \
        : "+v"(AX) : "v"(HU), "v"(DV))

#define DOT2(ACC, UA, UB) \
    ACC = __builtin_amdgcn_fdot2(__builtin_bit_cast(half2v, UA), \
                                 __builtin_bit_cast(half2v, UB), ACC, false)

// ---------------- single-pass edge scatter (+ folded precompute blocks) ----------------

__global__ __launch_bounds__(1024) void scatter_kernel(
        const int* __restrict__ src, const int* __restrict__ dst,
        int* __restrict__ deg, unsigned short* __restrict__ adj,
        int E, int nSB,
        const float* __restrict__ W3, const float* __restrict__ Wl,
        const float* __restrict__ b3, __half* __restrict__ W3lTh,
        float* __restrict__ b3l, const float* __restrict__ W2,
        __half* __restrict__ W2Th) {
    __shared__ float Wls[HIDDEN * NCLS];     // 9.7KB (precompute blocks only)
    int tid = threadIdx.x;

    if (blockIdx.x >= nSB) {                 // ---- folded precompute blocks ----
        int xb = blockIdx.x - nSB;
        if (xb < 3) {                        // W3lT fp16 transposed (+ b3l in xb==2)
            for (int i = tid; i < HIDDEN * NCLS; i += 1024) Wls[i] = Wl[i];
            __syncthreads();
            int o = xb * 1024 + tid;
            if (o < HIDDEN * NCLS) {
                int i = o / NCLS, j = o % NCLS;
                float acc = 0.f;
#pragma unroll 8
                for (int k = 0; k < HIDDEN; ++k) acc += W3[i * HIDDEN + k] * Wls[k * NCLS + j];
                W3lTh[j * WST + i] = __float2half(acc);   // transposed fp16
            }
            if (xb == 2 && tid >= 1000 && tid < 1000 + NCLS) {
                int j = tid - 1000;
                float acc = 0.f;
#pragma unroll 8
                for (int k = 0; k < HIDDEN; ++k) acc += b3[k] * Wls[k * NCLS + j];
                b3l[j] = acc;
            }
        } else {                              // xb 3..6: W2Th[n][k] = fp16(W2[k][n])
            int base = (xb - 3) * 4096;
#pragma unroll
            for (int r = 0; r < 4; ++r) {
                int idx = base + tid + 1024 * r;
                int k = idx >> 7, nn2 = idx & 127;
                W2Th[nn2 * HIDDEN + k] = __float2half(W2[idx]);
            }
        }
        return;
    }

    // ---- edge append (4 edges/thread): slot via deg atomic, store src ----
    int base = blockIdx.x * EPB;
    int cnt = min(EPB, E - base);
#pragma unroll
    for (int j = 0; j < 4; ++j) {
        int idx = tid + 1024 * j;
        if (idx < cnt) {
            int e = base + idx;
            int s = src[e], d = dst[e];
            int slot = atomicAdd(&deg[d], 1);
            if (slot < CAPA)                  // hard guard (balls-in-bins: never hit)
                adj[(long)d * CAPA + slot] = (unsigned short)s;
        }
    }
}

// ---------------- build2: dinv + x16h + gcnt (trivial pass) ----------------

__global__ __launch_bounds__(1024) void build_kernel(
        const int* __restrict__ deg, const float* __restrict__ x,
        const int* __restrict__ batch, float* __restrict__ dinv,
        float* __restrict__ gcnt, __half* __restrict__ x16h, int n) {
    long idx = (long)blockIdx.x * 1024 + threadIdx.x;
    if (idx >= (long)n * 16) return;
    int i = (int)(idx >> 4), j = (int)(idx & 15);
    float di = 1.0f / sqrtf((float)(deg[i] + 1));
    if (j == 0) {
        dinv[i] = di;
        atomicAdd(&gcnt[batch[i]], 1.0f);
    }
    float xv = (j < F_IN) ? x[(long)i * F_IN + j] * di : 0.f;
    x16h[(long)i * 16 + j] = __float2half(xv);
}

// ---------------- layer 1 fused: agg(x16h) + GEMM W1 + relu -> h1 fp16 ----------------
// 1024 threads = 16 nodes/block. Self-loop = predicated own-row MIXFMA (grp==0).

__global__ __launch_bounds__(1024) void agg16_gemm_kernel(
        const __half* __restrict__ x16h, const unsigned short* __restrict__ adj,
        const int* __restrict__ deg,
        const float* __restrict__ dinv, const float* __restrict__ W1,
        const float* __restrict__ b1, __half* __restrict__ h1h, int n) {
    __shared__ float2 W1s[F_IN][64];
    __shared__ float2 bs[64];
    int tid = threadIdx.x;
    // stage W1 (F_IN*64 float2 = 704) with float4: 352 float4 over 1024 threads
    if (tid < 352) ((float4*)W1s)[tid] = ((const float4*)W1)[tid];
    if (tid >= 960) bs[tid - 960] = make_float2(b1[2 * (tid - 960)], b1[2 * (tid - 960) + 1]);
    __syncthreads();
    int node = (int)(((long)blockIdx.x * blockDim.x + tid) >> 6);
    int lane = tid & 63;
    if (node >= n) return;
    int grp = lane >> 4, f = lane & 15;
    float di = dinv[node];
    int dn = min(deg[node], CAPA);           // stored entries
    // whole adjacency list in registers: one coalesced 128B read per wave
    int idxv = (lane < dn) ? (int)adj[(long)node * CAPA + lane] : 0;
    const unsigned short* x16u = (const unsigned short*)x16h;
    float acc = 0.f;
    if (grp == 0) {                          // self-loop: x[i]*di*di (once)
        unsigned int v = x16u[(long)node * 16 + f];
        MIXFMA1(acc, v, di);
    }
    int eb = 0;
    for (; eb + 16 <= dn; eb += 16) {        // wave-uniform trip: shfl safe
        int s[4]; unsigned int v[4];
#pragma unroll
        for (int j = 0; j < 4; ++j) s[j] = __shfl(idxv, eb + grp + 4 * j);
#pragma unroll
        for (int j = 0; j < 4; ++j) v[j] = x16u[(long)s[j] * 16 + f];
#pragma unroll
        for (int j = 0; j < 4; ++j) MIXFMA1(acc, v[j], di);
    }
    if (eb + 8 <= dn) {                      // wave-uniform predicate: shfl safe
        int s0 = __shfl(idxv, eb + grp), s1 = __shfl(idxv, eb + grp + 4);
        unsigned int v0 = x16u[(long)s0 * 16 + f], v1 = x16u[(long)s1 * 16 + f];
        MIXFMA1(acc, v0, di);
        MIXFMA1(acc, v1, di);
        eb += 8;
    }
    // remainder (<8): UNIFORM exec — all lanes shfl, gather predicated
#pragma unroll
    for (int r = 0; r < 2; ++r) {
        int e = eb + grp + 4 * r;
        int s = __shfl(idxv, e & 63);
        if (e < dn) {
            unsigned int v = x16u[(long)s * 16 + f];
            MIXFMA1(acc, v, di);
        }
    }
    acc += __shfl_down(acc, 32);
    acc += __shfl_down(acc, 16);
    float z = acc;                       // already scaled by dinv (folded per-term)
    float2 o = bs[lane];
#pragma unroll
    for (int k = 0; k < F_IN; ++k) {
        float zk = __shfl(z, k);
        float2 w = W1s[k][lane];
        o.x += zk * w.x;
        o.y += zk * w.y;
    }
    __half2 h = __floats2half2_rn(fmaxf(o.x, 0.f), fmaxf(o.y, 0.f));
    ((__half2*)h1h)[(long)node * 64 + lane] = h;
}

// ---------------- layer-2 GEMM: MFMA f16, W2Th pre-converted ----------------

__global__ __launch_bounds__(256) void gemm_mfma_kernel(
        const __half* __restrict__ h1h, const __half* __restrict__ W2Th,
        const float* __restrict__ dinv, __half* __restrict__ hsh, int n) {
    __shared__ _Float16 W2T[128 * 136];    // [n][k], stride 136
    __shared__ _Float16 outs[64 * 136];    // [node][feat], stride 136
    int tid = threadIdx.x;
    for (int i = tid; i < 128 * 16; i += 256) {
        int r = i >> 4, q = i & 15;
        *(uint4*)&W2T[r * 136 + q * 8] = ((const uint4*)W2Th)[r * 16 + q];
    }
    int base = blockIdx.x * 64;
    int lane = tid & 63, wid = tid >> 6;
    int l15 = lane & 15, quad = lane >> 4;
    int arow = base + wid * 16 + l15;
    if (arow >= n) arow = n - 1;           // clamp: safe reads, invalid rows unwritten
    const _Float16* Aptr = (const _Float16*)h1h + (size_t)arow * 128;
    floatx4 acc[8];
#pragma unroll
    for (int t = 0; t < 8; ++t) acc[t] = (floatx4){0.f, 0.f, 0.f, 0.f};
    __syncthreads();
#pragma unroll
    for (int c = 0; c < 4; ++c) {
        half8 a = *(const half8*)(Aptr + c * 32 + quad * 8);
#pragma unroll
        for (int t = 0; t < 8; ++t) {
            half8 b = *(const half8*)(&W2T[(t * 16 + l15) * 136 + c * 32 + quad * 8]);
            acc[t] = __builtin_amdgcn_mfma_f32_16x16x32_f16(a, b, acc[t], 0, 0, 0);
        }
    }
    float dv[4];
#pragma unroll
    for (int r = 0; r < 4; ++r) {
        int nd = base + wid * 16 + quad * 4 + r;
        dv[r] = dinv[(nd < n) ? nd : 0];
    }
#pragma unroll
    for (int t = 0; t < 8; ++t)
#pragma unroll
        for (int r = 0; r < 4; ++r)
            outs[(wid * 16 + quad * 4 + r) * 136 + t * 16 + l15] = (_Float16)(acc[t][r] * dv[r]);
    __syncthreads();
    for (int i = tid; i < 64 * 16; i += 256) {
        int ln = i >> 4, qq = i & 15;
        long nd = base + ln;
        if (nd < n) {
            uint4 u = *(uint4*)&outs[ln * 136 + qq * 8];
            ((uint4*)hsh)[nd * 16 + qq] = u;
        }
    }
}

// ---------------- 128-wide agg (layer 2) FUSED with folded layer-3 GEMM ----------------
// h2 = relu(sum(hsh*di) + b2) per-wave, handed off as fp16 in LDS;
// y = (h2 @ W3l)*di via v_dot2_f32_f16 against transposed fp16 WsT rows.
// Wave-synchronous epilogue (no block barrier): hs[w] written+read by same wave.

__global__ __launch_bounds__(1024) void agg128h_y_kernel(
        const __half* __restrict__ hsh, const unsigned short* __restrict__ adj,
        const int* __restrict__ deg, const float* __restrict__ dinv,
        const float* __restrict__ bias, const __half* __restrict__ W3lTh,
        __half* __restrict__ ys, int n) {
    __shared__ _Float16 Ws[32 * WST];    // WsT[j][k] fp16, stride 136 (8704B)
    __shared__ _Float16 hs[16][HIDDEN];  // per-wave h2 handoff, fp16 (4KB)
    int tid = threadIdx.x;
    // 8704B = 544 float4 over 1024 threads
    if (tid < 544) ((float4*)Ws)[tid] = ((const float4*)W3lTh)[tid];
    __syncthreads();                     // Ws staging only
    int node = (int)(((long)blockIdx.x * blockDim.x + tid) >> 6);
    if (node >= n) return;
    int lane = tid & 63, w = tid >> 6;
    int grp = lane >> 5, q = lane & 31;
    float di = dinv[node];
    int dn = min(deg[node], CAPA);
    // whole adjacency list in registers: one coalesced 128B read per wave
    int idxv = (lane < dn) ? (int)adj[(long)node * CAPA + lane] : 0;
    float4 acc = make_float4(0.f, 0.f, 0.f, 0.f);
    if (grp == 0) {                      // self-loop contribution (once)
        uint2 u = ((const uint2*)hsh)[(long)node * 32 + q];
        MIXFMA4(acc, u.x, u.y, di);
    }
    int eb = 0;
    for (; eb + 16 <= dn; eb += 16) {        // wave-uniform trip: shfl safe
        int s[8]; uint2 u[8];
#pragma unroll
        for (int j = 0; j < 8; ++j) s[j] = __shfl(idxv, eb + grp + 2 * j);
#pragma unroll
        for (int j = 0; j < 8; ++j) u[j] = ((const uint2*)hsh)[(long)s[j] * 32 + q];
#pragma unroll
        for (int j = 0; j < 8; ++j) MIXFMA4(acc, u[j].x, u[j].y, di);
    }
    if (eb + 8 <= dn) {                      // wave-uniform predicate: shfl safe
        int s[4]; uint2 u[4];
#pragma unroll
        for (int j = 0; j < 4; ++j) s[j] = __shfl(idxv, eb + grp + 2 * j);
#pragma unroll
        for (int j = 0; j < 4; ++j) u[j] = ((const uint2*)hsh)[(long)s[j] * 32 + q];
#pragma unroll
        for (int j = 0; j < 4; ++j) MIXFMA4(acc, u[j].x, u[j].y, di);
        eb += 8;
    }
    // remainder (<8): UNIFORM exec — all lanes shfl, gather predicated
#pragma unroll
    for (int r = 0; r < 4; ++r) {
        int e = eb + grp + 2 * r;
        int s = __shfl(idxv, e & 63);
        if (e < dn) {
            uint2 u = ((const uint2*)hsh)[(long)s * 32 + q];
            MIXFMA4(acc, u.x, u.y, di);
        }
    }
    acc.x += __shfl_down(acc.x, 32);
    acc.y += __shfl_down(acc.y, 32);
    acc.z += __shfl_down(acc.z, 32);
    acc.w += __shfl_down(acc.w, 32);
    if (grp == 0) {                      // lanes 0..31 hold full h2 row (pre-scaled)
        float4 b = ((const float4*)bias)[q];
        __half2 p01 = __floats2half2_rn(fmaxf(acc.x + b.x, 0.f), fmaxf(acc.y + b.y, 0.f));
        __half2 p23 = __floats2half2_rn(fmaxf(acc.z + b.z, 0.f), fmaxf(acc.w + b.w, 0.f));
        uint2 hv = make_uint2(*(unsigned int*)&p01, *(unsigned int*)&p23);
        *(uint2*)&hs[w][q * 4] = hv;     // fp16 h2 handoff
    }
    asm volatile("s_waitcnt lgkmcnt(0)" ::: "memory");   // wave-local handoff
    // y_j = sum_k h2[k]*WsT[j][k]: lane j does k<64, lane j+32 does k>=64
    float yacc = 0.f;
    int kbase = grp * 64;
    if (q < NCLS) {
#pragma unroll
        for (int kk = 0; kk < 8; ++kk) {
            int k0 = kbase + kk * 8;
            uint4 ua = *(uint4*)&hs[w][k0];          // broadcast within grp
            uint4 ub = *(uint4*)&Ws[q * WST + k0];   // contiguous b128 row
            DOT2(yacc, ua.x, ub.x);
            DOT2(yacc, ua.y, ub.y);
            DOT2(yacc, ua.z, ub.z);
            DOT2(yacc, ua.w, ub.w);
        }
    }
    yacc += __shfl_down(yacc, 32);       // lane j<19 now has full dot
    if (lane < NCLS)
        ys[(long)node * 32 + lane] = __float2half(yacc * di);
    // cols 19..31 left as garbage: pool kernel's c0<NCLS guards discard them
}

// ---------------- layer-3 agg + pool (LDS per-graph partials) + head ----------------
// 1024 threads = 16 nodes/block. batch sorted => block spans few graph ids;
// partials staged in pg[32][24] (LDS atomics), flushed with ~span*19 global
// atomics per block. slot>=32 falls back to direct global atomics (hard guard).

__global__ __launch_bounds__(1024) void agg24h_pool_kernel(
        const __half* __restrict__ ys, const unsigned short* __restrict__ adj,
        const int* __restrict__ deg, const float* __restrict__ dinv,
        const int* __restrict__ batch, float* __restrict__ pool, int n) {
    __shared__ float pg[32 * 24];
    __shared__ int g0s;
    int tid = threadIdx.x;
    long nbase = (long)blockIdx.x * 16;      // first node of block
    if (tid == 0) g0s = batch[nbase < n ? nbase : (n - 1)];
    if (tid < 32 * 24) pg[tid] = 0.f;
    __syncthreads();
    int g0 = g0s;
    int node = (int)(nbase + (tid >> 6));
    int lane = tid & 63;
    bool active = node < n;
    int grp = lane >> 4, f = lane & 15;
    float2 acc = {0.f, 0.f};
    if (active) {
        float sc = dinv[node];
        int dn = min(deg[node], CAPA);
        // whole adjacency list in registers: one coalesced 128B read per wave
        int idxv = (lane < dn) ? (int)adj[(long)node * CAPA + lane] : 0;
        if (grp == 0) {                      // self-loop contribution (once)
            unsigned int u = ((const unsigned int*)ys)[(long)node * 16 + f];
            MIXFMA2(acc.x, acc.y, u, sc);
        }
        int eb = 0;
        for (; eb + 32 <= dn; eb += 32) {        // wave-uniform trip: shfl safe
            int s[8]; unsigned int u[8];
#pragma unroll
            for (int j = 0; j < 8; ++j) s[j] = __shfl(idxv, eb + grp + 4 * j);
#pragma unroll
            for (int j = 0; j < 8; ++j) u[j] = ((const unsigned int*)ys)[(long)s[j] * 16 + f];
#pragma unroll
            for (int j = 0; j < 8; ++j) MIXFMA2(acc.x, acc.y, u[j], sc);
        }
        if (eb + 16 <= dn) {                     // wave-uniform predicate: shfl safe
            int s[4]; unsigned int u[4];
#pragma unroll
            for (int j = 0; j < 4; ++j) s[j] = __shfl(idxv, eb + grp + 4 * j);
#pragma unroll
            for (int j = 0; j < 4; ++j) u[j] = ((const unsigned int*)ys)[(long)s[j] * 16 + f];
#pragma unroll
            for (int j = 0; j < 4; ++j) MIXFMA2(acc.x, acc.y, u[j], sc);
            eb += 16;
        }
        // remainder (<16): UNIFORM exec within wave — all lanes shfl, gather predicated
#pragma unroll
        for (int r = 0; r < 4; ++r) {
            int e = eb + grp + 4 * r;
            int s = __shfl(idxv, e & 63);
            if (e < dn) {
                unsigned int u = ((const unsigned int*)ys)[(long)s * 16 + f];
                MIXFMA2(acc.x, acc.y, u, sc);
            }
        }
        acc.x += __shfl_down(acc.x, 32);
        acc.y += __shfl_down(acc.y, 32);
        acc.x += __shfl_down(acc.x, 16);
        acc.y += __shfl_down(acc.y, 16);
        if (lane < 16) {
            int g = batch[node];
            int slot = g - g0;                   // >=0: batch sorted
            int c0 = 2 * f;
            if (slot < 32) {                     // LDS partial (common case)
                if (c0 < NCLS) atomicAdd(&pg[slot * 24 + c0], acc.x);
                if (c0 + 1 < NCLS) atomicAdd(&pg[slot * 24 + c0 + 1], acc.y);
            } else {                             // hard-guarded fallback
                if (c0 < NCLS) atomicAdd(&pool[(long)g * 24 + c0], acc.x);
                if (c0 + 1 < NCLS) atomicAdd(&pool[(long)g * 24 + c0 + 1], acc.y);
            }
        }
    }
    __syncthreads();                             // uniform: all threads arrive
    if (tid < 32 * 24) {
        float v = pg[tid];
        if (v != 0.f) {                          // skip empty slots/cols
            int slot = tid / 24, c = tid - slot * 24;
            atomicAdd(&pool[(long)(g0 + slot) * 24 + c], v);
        }
    }
}

__global__ void final_kernel(const float* __restrict__ pool, const float* __restrict__ cnt,
                             const float* __restrict__ b3l, const float* __restrict__ bl,
                             float* __restrict__ out, int G) {
    int i = blockIdx.x * blockDim.x + threadIdx.x;
    if (i >= G * NCLS) return;
    int g = i / NCLS, j = i % NCLS;
    float c = cnt[g];
    out[i] = (c > 0.f) ? pool[(long)g * 24 + j] / c + b3l[j] + bl[j] : bl[j];
}

// ---------------- launch ----------------

static inline size_t align256(size_t x) { return (x + 255) & ~(size_t)255; }

extern "C" void kernel_launch(void* const* d_in, const int* in_sizes, int n_in,
                              void* d_out, int out_size, void* d_ws, size_t ws_size,
                              hipStream_t stream) {
    const float* x    = (const float*)d_in[0];
    const int*   ei   = (const int*)d_in[1];
    const int*   batch= (const int*)d_in[2];
    const float* W1   = (const float*)d_in[3];
    const float* b1   = (const float*)d_in[4];
    const float* W2   = (const float*)d_in[5];
    const float* b2   = (const float*)d_in[6];
    const float* W3   = (const float*)d_in[7];
    const float* b3   = (const float*)d_in[8];
    const float* Wl   = (const float*)d_in[9];
    const float* bl   = (const float*)d_in[10];
    float* out = (float*)d_out;

    const int N = in_sizes[0] / F_IN;
    const int E = in_sizes[1] / 2;
    const int G = out_size / NCLS;
    const int* src = ei;
    const int* dst = ei + E;
    const int nSB = (E + EPB - 1) / EPB;

    // workspace carve-up
    char* p = (char*)d_ws;
    size_t off = 0;
    unsigned short* adj    = (unsigned short*)(p + off); off = align256(off + (size_t)N * CAPA * 2);
    float*          dinv   = (float*)(p + off);          off = align256(off + (size_t)N * 4);
    __half*         x16h   = (__half*)(p + off);         off = align256(off + (size_t)N * 16 * 2);
    __half*         h1h    = (__half*)(p + off);         off = align256(off + (size_t)N * HIDDEN * 2);
    __half*         hsh    = (__half*)(p + off);         off = align256(off + (size_t)N * HIDDEN * 2);
    __half*         y32h   = (__half*)(p + off);         off = align256(off + (size_t)N * 32 * 2);
    __half*         W2Th   = (__half*)(p + off);         off = align256(off + (size_t)HIDDEN * HIDDEN * 2);
    __half*         W3lTh  = (__half*)(p + off);         off = align256(off + (size_t)32 * WST * 2);
    float*          b3l    = (float*)(p + off);          off = align256(off + (size_t)NCLS * 4);
    float*          pool   = (float*)(p + off);          // pool | gcnt | deg contiguous
    float*          gcnt   = pool + (size_t)G * 24;
    int*            deg    = (int*)(pool + (size_t)G * 25);
    off = align256(off + (size_t)G * 25 * 4 + (size_t)N * 4);
    (void)ws_size; (void)n_in;

    // one memset zeroes pool, gcnt, and deg
    hipMemsetAsync(pool, 0, (size_t)G * 25 * 4 + (size_t)N * 4, stream);

    // single-pass adjacency build (+ folded W3lT / W2Th precompute blocks)
    scatter_kernel<<<nSB + 7, 1024, 0, stream>>>(src, dst, deg, adj, E, nSB,
                                                 W3, Wl, b3, W3lTh, b3l, W2, W2Th);
    build_kernel<<<(int)(((long)N * 16 + 1023) / 1024), 1024, 0, stream>>>(
        deg, x, batch, dinv, gcnt, x16h, N);

    const int aggBlocks16 = (N + 15) / 16;  // 16 waves/block, wave per node

    // layer 1 fused: h1 = relu((sum x16h*di)@W1 + b1) -> fp16
    agg16_gemm_kernel<<<aggBlocks16, 1024, 0, stream>>>(x16h, adj, deg, dinv, W1, b1, h1h, N);

    // layer 2: hsh = half((h1@W2)*dinv) row-major [MFMA]
    gemm_mfma_kernel<<<(N + 63) / 64, 256, 0, stream>>>(h1h, W2Th, dinv, hsh, N);

    // layer-2 agg + folded layer-3 GEMM fused: ys = ((relu(sum hsh*di + b2)) @ W3l)*di
    agg128h_y_kernel<<<aggBlocks16, 1024, 0, stream>>>(hsh, adj, deg, dinv, b2, W3lTh, y32h, N);

    // layer-3 agg + pool (LDS per-graph partials), then head
    agg24h_pool_kernel<<<aggBlocks16, 1024, 0, stream>>>(y32h, adj, deg, dinv, batch, pool, N);
    final_kernel<<<(G * NCLS + 255) / 256, 256, 0, stream>>>(pool, gcnt, b3l, bl, out, G);
}

// Round 13
// 201.696 us; speedup vs baseline: 1.2418x; 1.2418x over previous
//
#include <hip/hip_runtime.h>
#include <hip/hip_bf16.h>
#include <hip/hip_fp16.h>

// GCN2: 3x GCNConv(relu,relu,none) + global_mean_pool + linear head.
// R29: REVERT R28 (single-pass adj build: scattered 2B stores caused 32x
// write amplification, WRITE_SIZE 3MB->45MB, scatter 55us -> total 250us).
// Restores R25 exactly (best measured: 200.7us). Bucketed 2-phase CSR build
// keeps writes DENSE (LDS-staged coalesced bents/csr16) — that's why it wins.
// R25: pool LDS per-graph partials (16 nodes/block, pg[32][24]).
// R24: divergent-barrier fix. R23: scatter/build 1024 threads.
// R22: fp16 y-dot epilogue (WsT transposed fp16 + v_dot2_f32_f16).
// R21: 1024-thread agg blocks (16 nodes) amortize weight staging 4x.
// R20: uniform-exec remainder loops. R19: register-resident CSR indices.
// R18: v_fma_mix_f32 gather accumulate (dinv folded), wave-local epilogue.
// R17: fused gemm_y32h into agg128h. Base (R13): bucketed CSR build,
// fused agg16+W1, MFMA f16 layer-2 GEMM, folded W3@Wl head, atomic pool.
// Failed experiments (do not retry): R26 MFMA y-epilogue (block barrier
// serializes gather waves), R27 packed-uint agg16 gather (ILP width loss),
// R28 single-pass adj build (write amplification).

#define HIDDEN 128
#define F_IN 11
#define NCLS 19
#define NBITS 8
#define NB 256
#define RNODES 256
#define EPB 4096
#define OUTL_CAP 5376
#define WST 136   // WsT row stride in halves (16B-aligned rows, low bank conflict)

typedef _Float16 half8 __attribute__((ext_vector_type(8)));
typedef _Float16 half2v __attribute__((ext_vector_type(2)));
typedef float floatx4 __attribute__((ext_vector_type(4)));

// acc.{x,y,z,w} += fp16{lo(UX),hi(UX),lo(UY),hi(UY)} * DV   (one inst each)
#define MIXFMA4(A, UX, UY, DV) \
    asm("v_fma_mix_f32 %0, %4, %5, %0 op_sel_hi:[1,0,0]\n\t" \
        "v_fma_mix_f32 %1, %4, %5, %1 op_sel:[1,0,0] op_sel_hi:[1,0,0]\n\t" \
        "v_fma_mix_f32 %2, %6, %5, %2 op_sel_hi:[1,0,0]\n\t" \
        "v_fma_mix_f32 %3, %6, %5, %3 op_sel:[1,0,0] op_sel_hi:[1,0,0]" \
        : "+v"(A.x), "+v"(A.y), "+v"(A.z), "+v"(A.w) \
        : "v"(UX), "v"(DV), "v"(UY))

#define MIXFMA2(AX, AY, UU, DV) \
    asm("v_fma_mix_f32 %0, %2, %3, %0 op_sel_hi:[1,0,0]\n\t" \
        "v_fma_mix_f32 %1, %2, %3, %1 op_sel:[1,0,0] op_sel_hi:[1,0,0]" \
        : "+v"(AX), "+v"(AY) : "v"(UU), "v"(DV))

#define MIXFMA1(AX, HU, DV) \
    asm("v_fma_mix_f32 %0, %1, %2, %0 op_sel_hi:[1,0,0]" \
        : "+v"(AX) : "v"(HU), "v"(DV))

#define DOT2(ACC, UA, UB) \
    ACC = __builtin_amdgcn_fdot2(__builtin_bit_cast(half2v, UA), \
                                 __builtin_bit_cast(half2v, UB), ACC, false)

// ---------------- scatter (+ folded w3lT / W2 conversion blocks), 1024 thr ----------------

__global__ __launch_bounds__(1024) void scatter_kernel(
        const int* __restrict__ src, const int* __restrict__ dst,
        int* __restrict__ bcur, unsigned int* __restrict__ bents,
        int E, int cap, int nSB,
        const float* __restrict__ W3, const float* __restrict__ Wl,
        const float* __restrict__ b3, __half* __restrict__ W3lTh,
        float* __restrict__ b3l, const float* __restrict__ W2,
        __half* __restrict__ W2Th) {
    __shared__ int hist[NB];
    __shared__ int binoff[NB];
    __shared__ int runrel[NB];
    __shared__ unsigned int ebuf[EPB];
    __shared__ unsigned short binOf[EPB];
    __shared__ int cw[4];
    int tid = threadIdx.x, lane = tid & 63, w = tid >> 6;

    if (blockIdx.x >= nSB) {                 // ---- folded precompute blocks ----
        int xb = blockIdx.x - nSB;
        if (xb < 3) {                        // W3lT fp16 transposed (+ b3l in xb==2)
            float* Wls = (float*)ebuf;       // alias: 128*19 floats = 9.7KB
            for (int i = tid; i < HIDDEN * NCLS; i += 1024) Wls[i] = Wl[i];
            __syncthreads();
            int o = xb * 1024 + tid;
            if (o < HIDDEN * NCLS) {
                int i = o / NCLS, j = o % NCLS;
                float acc = 0.f;
#pragma unroll 8
                for (int k = 0; k < HIDDEN; ++k) acc += W3[i * HIDDEN + k] * Wls[k * NCLS + j];
                W3lTh[j * WST + i] = __float2half(acc);   // transposed fp16
            }
            if (xb == 2 && tid >= 1000 && tid < 1000 + NCLS) {
                int j = tid - 1000;
                float acc = 0.f;
#pragma unroll 8
                for (int k = 0; k < HIDDEN; ++k) acc += b3[k] * Wls[k * NCLS + j];
                b3l[j] = acc;
            }
        } else {                              // xb 3..6: W2Th[n][k] = fp16(W2[k][n])
            int base = (xb - 3) * 4096;
#pragma unroll
            for (int r = 0; r < 4; ++r) {
                int idx = base + tid + 1024 * r;
                int k = idx >> 7, nn2 = idx & 127;
                W2Th[nn2 * HIDDEN + k] = __float2half(W2[idx]);
            }
        }
        return;
    }

    // ---- scatter proper (4 edges/thread) ----
    int base = blockIdx.x * EPB;
    int cnt = min(EPB, E - base);
    if (tid < NB) hist[tid] = 0;
    __syncthreads();
    unsigned int pk[4];
    int rk[4];
#pragma unroll
    for (int j = 0; j < 4; ++j) {
        int idx = tid + 1024 * j;
        if (idx < cnt) {
            int e = base + idx;
            int s = src[e], d = dst[e];
            pk[j] = (unsigned int)s | ((unsigned int)d << 16);
            int bin = d >> NBITS;
            int r = atomicAdd(&hist[bin], 1);
            rk[j] = r | (bin << 16);
        } else rk[j] = -1;
    }
    __syncthreads();
    if (tid < NB) {                            // first 4 waves scan 256 bins
        int v = hist[tid], xv = v;
#pragma unroll
        for (int d = 1; d < 64; d <<= 1) {
            int t = __shfl_up(xv, d, 64);
            if (lane >= d) xv += t;
        }
        if (lane == 63) cw[w] = xv;
        binoff[tid] = xv - v;                  // exclusive within wave (temp)
        runrel[tid] = v ? atomicAdd(&bcur[tid], v) : 0;
    }
    __syncthreads();                           // cw[] visible to all
    if (tid < NB) {
        int waveoff = 0;
        for (int wi = 0; wi < w; ++wi) waveoff += cw[wi];
        binoff[tid] += waveoff;
    }
    __syncthreads();
#pragma unroll
    for (int j = 0; j < 4; ++j) {
        if (rk[j] >= 0) {
            int bin = rk[j] >> 16, r = rk[j] & 0xFFFF;
            int pos = binoff[bin] + r;
            ebuf[pos] = pk[j];
            binOf[pos] = (unsigned short)bin;
        }
    }
    __syncthreads();
    for (int i = tid; i < cnt; i += 1024) {
        int bin = binOf[i];
        int rel = runrel[bin] + (i - binoff[bin]);
        if (rel < cap)                          // hard guard: never cross regions
            bents[bin * cap + rel] = ebuf[i];
    }
}

// per bucket (256 nodes): counts -> scan -> LDS scatter -> dense writes. 1024 threads.
__global__ __launch_bounds__(1024) void build_kernel(
        const unsigned int* __restrict__ bents, const int* __restrict__ bcur,
        const float* __restrict__ x, const int* __restrict__ batch,
        int2* __restrict__ begend, unsigned short* __restrict__ csr16,
        float* __restrict__ dinv, float* __restrict__ gcnt,
        __half* __restrict__ x16h, int n, int cap, int rst) {
    __shared__ int counts[RNODES];
    __shared__ int lcur[RNODES];
    __shared__ unsigned short outl[OUTL_CAP];
    __shared__ int wsums[4];
    int tid = threadIdx.x;          // 1024
    int lane = tid & 63, w = tid >> 6;
    int b = blockIdx.x;
    int base = b << NBITS;
    int nn = min(RNODES, n - base);
    int ebase = b * cap;
    int ecnt = min(bcur[b], cap);   // hard guard
    int st = b * rst;
    if (tid < RNODES) counts[tid] = 0;
    __syncthreads();
    for (int e = tid; e < ecnt; e += 1024)
        atomicAdd(&counts[(bents[ebase + e] >> 16) - base], 1);
    __syncthreads();
    int v = 0, xv = 0;
    if (tid < RNODES) {             // first 4 waves scan 256 entries
        v = (tid < nn) ? counts[tid] + 1 : 0;
        xv = v;
#pragma unroll
        for (int d = 1; d < 64; d <<= 1) {
            int t = __shfl_up(xv, d, 64);
            if (lane >= d) xv += t;
        }
        if (lane == 63) wsums[w] = xv;
    }
    __syncthreads();
    if (tid < nn) {
        int waveoff = 0;
        for (int wi = 0; wi < w; ++wi) waveoff += wsums[wi];
        int excl = waveoff + xv - v;
        lcur[tid] = excl + 1;
        outl[excl] = (unsigned short)(base + tid);        // self-loop slot 0
        begend[base + tid] = make_int2(st + excl, st + excl + v);
        atomicAdd(&gcnt[batch[base + tid]], 1.0f);
    }
    __syncthreads();
    for (int e = tid; e < ecnt; e += 1024) {
        unsigned int pk = bents[ebase + e];
        int i = (int)(pk >> 16) - base;
        int r = atomicAdd(&lcur[i], 1);
        outl[r] = (unsigned short)(pk & 0xFFFFu);
    }
    __syncthreads();
    int total = ecnt + nn;
    for (int i = tid; i < total; i += 1024)
        csr16[st + i] = outl[i];
    for (int idx = tid; idx < nn * 16; idx += 1024) {
        int i = idx >> 4, j = idx & 15;
        float di = 1.0f / sqrtf((float)(counts[i] + 1));
        if (j == 0) dinv[base + i] = di;
        float xv2 = (j < F_IN) ? x[(long)(base + i) * F_IN + j] * di : 0.f;
        x16h[(long)(base + i) * 16 + j] = __float2half(xv2);
    }
}

// ---------------- layer 1 fused: agg(x16h) + GEMM W1 + relu -> h1 fp16 ----------------
// 1024 threads = 16 nodes/block (staging amortized 4x vs 256-thread blocks).

__global__ __launch_bounds__(1024) void agg16_gemm_kernel(
        const __half* __restrict__ x16h, const int2* __restrict__ begend,
        const unsigned short* __restrict__ csr16,
        const float* __restrict__ dinv, const float* __restrict__ W1,
        const float* __restrict__ b1, __half* __restrict__ h1h, int n) {
    __shared__ float2 W1s[F_IN][64];
    __shared__ float2 bs[64];
    int tid = threadIdx.x;
    // stage W1 (F_IN*64 float2 = 704) with float4: 352 float4 over 1024 threads
    if (tid < 352) ((float4*)W1s)[tid] = ((const float4*)W1)[tid];
    if (tid >= 960) bs[tid - 960] = make_float2(b1[2 * (tid - 960)], b1[2 * (tid - 960) + 1]);
    __syncthreads();
    int node = (int)(((long)blockIdx.x * blockDim.x + tid) >> 6);
    int lane = tid & 63;
    if (node >= n) return;
    int grp = lane >> 4, f = lane & 15;
    float di = dinv[node];
    int2 be = begend[node];
    int beg = be.x, end = be.y;
    int deg = end - beg;
    // whole adjacency list in registers: one coalesced 128B read per wave
    int idxv = (lane < deg) ? (int)csr16[beg + lane] : 0;
    int lim = (deg > 64) ? beg + 64 : end;
    const unsigned short* x16u = (const unsigned short*)x16h;
    float acc = 0.f;
    int eb = beg;
    for (; eb + 16 <= lim; eb += 16) {       // wave-uniform trip: shfl safe
        int off = eb - beg;
        int s[4]; unsigned int v[4];
#pragma unroll
        for (int j = 0; j < 4; ++j) s[j] = __shfl(idxv, off + grp + 4 * j);
#pragma unroll
        for (int j = 0; j < 4; ++j) v[j] = x16u[(long)s[j] * 16 + f];
#pragma unroll
        for (int j = 0; j < 4; ++j) MIXFMA1(acc, v[j], di);
    }
    if (eb + 8 <= lim) {                     // wave-uniform predicate: shfl safe
        int off = eb - beg;
        int s0 = __shfl(idxv, off + grp), s1 = __shfl(idxv, off + grp + 4);
        unsigned int v0 = x16u[(long)s0 * 16 + f], v1 = x16u[(long)s1 * 16 + f];
        MIXFMA1(acc, v0, di);
        MIXFMA1(acc, v1, di);
        eb += 8;
    }
    // remainder (<8): UNIFORM exec — all lanes shfl, gather predicated
#pragma unroll
    for (int r = 0; r < 2; ++r) {
        int e = eb + grp + 4 * r;
        int s = __shfl(idxv, (e - beg) & 63);   // clamp only matters when e>=lim
        if (e < lim) {
            unsigned int v = x16u[(long)s * 16 + f];
            MIXFMA1(acc, v, di);
        }
    }
    for (int e = lim + grp; e < end; e += 4) {  // deg>64 fallback: direct loads
        unsigned int v = x16u[(long)csr16[e] * 16 + f];
        MIXFMA1(acc, v, di);
    }
    acc += __shfl_down(acc, 32);
    acc += __shfl_down(acc, 16);
    float z = acc;                       // already scaled by dinv (folded per-term)
    float2 o = bs[lane];
#pragma unroll
    for (int k = 0; k < F_IN; ++k) {
        float zk = __shfl(z, k);
        float2 w = W1s[k][lane];
        o.x += zk * w.x;
        o.y += zk * w.y;
    }
    __half2 h = __floats2half2_rn(fmaxf(o.x, 0.f), fmaxf(o.y, 0.f));
    ((__half2*)h1h)[(long)node * 64 + lane] = h;
}

// ---------------- layer-2 GEMM: MFMA f16, W2Th pre-converted ----------------

__global__ __launch_bounds__(256) void gemm_mfma_kernel(
        const __half* __restrict__ h1h, const __half* __restrict__ W2Th,
        const float* __restrict__ dinv, __half* __restrict__ hsh, int n) {
    __shared__ _Float16 W2T[128 * 136];    // [n][k], stride 136
    __shared__ _Float16 outs[64 * 136];    // [node][feat], stride 136
    int tid = threadIdx.x;
    for (int i = tid; i < 128 * 16; i += 256) {
        int r = i >> 4, q = i & 15;
        *(uint4*)&W2T[r * 136 + q * 8] = ((const uint4*)W2Th)[r * 16 + q];
    }
    int base = blockIdx.x * 64;
    int lane = tid & 63, wid = tid >> 6;
    int l15 = lane & 15, quad = lane >> 4;
    int arow = base + wid * 16 + l15;
    if (arow >= n) arow = n - 1;           // clamp: safe reads, invalid rows unwritten
    const _Float16* Aptr = (const _Float16*)h1h + (size_t)arow * 128;
    floatx4 acc[8];
#pragma unroll
    for (int t = 0; t < 8; ++t) acc[t] = (floatx4){0.f, 0.f, 0.f, 0.f};
    __syncthreads();
#pragma unroll
    for (int c = 0; c < 4; ++c) {
        half8 a = *(const half8*)(Aptr + c * 32 + quad * 8);
#pragma unroll
        for (int t = 0; t < 8; ++t) {
            half8 b = *(const half8*)(&W2T[(t * 16 + l15) * 136 + c * 32 + quad * 8]);
            acc[t] = __builtin_amdgcn_mfma_f32_16x16x32_f16(a, b, acc[t], 0, 0, 0);
        }
    }
    float dv[4];
#pragma unroll
    for (int r = 0; r < 4; ++r) {
        int nd = base + wid * 16 + quad * 4 + r;
        dv[r] = dinv[(nd < n) ? nd : 0];
    }
#pragma unroll
    for (int t = 0; t < 8; ++t)
#pragma unroll
        for (int r = 0; r < 4; ++r)
            outs[(wid * 16 + quad * 4 + r) * 136 + t * 16 + l15] = (_Float16)(acc[t][r] * dv[r]);
    __syncthreads();
    for (int i = tid; i < 64 * 16; i += 256) {
        int ln = i >> 4, qq = i & 15;
        long nd = base + ln;
        if (nd < n) {
            uint4 u = *(uint4*)&outs[ln * 136 + qq * 8];
            ((uint4*)hsh)[nd * 16 + qq] = u;
        }
    }
}

// ---------------- 128-wide agg (layer 2) FUSED with folded layer-3 GEMM ----------------
// h2 = relu(sum(hsh*di) + b2) per-wave, handed off as fp16 in LDS;
// y = (h2 @ W3l)*di via v_dot2_f32_f16 against transposed fp16 WsT rows.
// Wave-synchronous epilogue (no block barrier): hs[w] written+read by same wave.

__global__ __launch_bounds__(1024) void agg128h_y_kernel(
        const __half* __restrict__ hsh, const int2* __restrict__ begend,
        const unsigned short* __restrict__ csr16, const float* __restrict__ dinv,
        const float* __restrict__ bias, const __half* __restrict__ W3lTh,
        __half* __restrict__ ys, int n) {
    __shared__ _Float16 Ws[32 * WST];    // WsT[j][k] fp16, stride 136 (8704B)
    __shared__ _Float16 hs[16][HIDDEN];  // per-wave h2 handoff, fp16 (4KB)
    int tid = threadIdx.x;
    // 8704B = 544 float4 over 1024 threads
    if (tid < 544) ((float4*)Ws)[tid] = ((const float4*)W3lTh)[tid];
    __syncthreads();                     // Ws staging only
    int node = (int)(((long)blockIdx.x * blockDim.x + tid) >> 6);
    if (node >= n) return;
    int lane = tid & 63, w = tid >> 6;
    int grp = lane >> 5, q = lane & 31;
    float di = dinv[node];
    int2 be = begend[node];
    int beg = be.x, end = be.y;
    int deg = end - beg;
    // whole adjacency list in registers: one coalesced 128B read per wave
    int idxv = (lane < deg) ? (int)csr16[beg + lane] : 0;
    int lim = (deg > 64) ? beg + 64 : end;
    float4 acc = make_float4(0.f, 0.f, 0.f, 0.f);
    int eb = beg;
    for (; eb + 16 <= lim; eb += 16) {       // wave-uniform trip: shfl safe
        int off = eb - beg;
        int s[8]; uint2 u[8];
#pragma unroll
        for (int j = 0; j < 8; ++j) s[j] = __shfl(idxv, off + grp + 2 * j);
#pragma unroll
        for (int j = 0; j < 8; ++j) u[j] = ((const uint2*)hsh)[(long)s[j] * 32 + q];
#pragma unroll
        for (int j = 0; j < 8; ++j) MIXFMA4(acc, u[j].x, u[j].y, di);
    }
    if (eb + 8 <= lim) {                     // wave-uniform predicate: shfl safe
        int off = eb - beg;
        int s[4]; uint2 u[4];
#pragma unroll
        for (int j = 0; j < 4; ++j) s[j] = __shfl(idxv, off + grp + 2 * j);
#pragma unroll
        for (int j = 0; j < 4; ++j) u[j] = ((const uint2*)hsh)[(long)s[j] * 32 + q];
#pragma unroll
        for (int j = 0; j < 4; ++j) MIXFMA4(acc, u[j].x, u[j].y, di);
        eb += 8;
    }
    // remainder (<8): UNIFORM exec — all lanes shfl, gather predicated
#pragma unroll
    for (int r = 0; r < 4; ++r) {
        int e = eb + grp + 2 * r;
        int s = __shfl(idxv, (e - beg) & 63);
        if (e < lim) {
            uint2 u = ((const uint2*)hsh)[(long)s * 32 + q];
            MIXFMA4(acc, u.x, u.y, di);
        }
    }
    for (int e = lim + grp; e < end; e += 2) {  // deg>64 fallback: direct loads
        uint2 u = ((const uint2*)hsh)[(long)csr16[e] * 32 + q];
        MIXFMA4(acc, u.x, u.y, di);
    }
    acc.x += __shfl_down(acc.x, 32);
    acc.y += __shfl_down(acc.y, 32);
    acc.z += __shfl_down(acc.z, 32);
    acc.w += __shfl_down(acc.w, 32);
    if (grp == 0) {                      // lanes 0..31 hold full h2 row (pre-scaled)
        float4 b = ((const float4*)bias)[q];
        __half2 p01 = __floats2half2_rn(fmaxf(acc.x + b.x, 0.f), fmaxf(acc.y + b.y, 0.f));
        __half2 p23 = __floats2half2_rn(fmaxf(acc.z + b.z, 0.f), fmaxf(acc.w + b.w, 0.f));
        uint2 hv = make_uint2(*(unsigned int*)&p01, *(unsigned int*)&p23);
        *(uint2*)&hs[w][q * 4] = hv;     // fp16 h2 handoff
    }
    asm volatile("s_waitcnt lgkmcnt(0)" ::: "memory");   // wave-local handoff
    // y_j = sum_k h2[k]*WsT[j][k]: lane j does k<64, lane j+32 does k>=64
    float yacc = 0.f;
    int kbase = grp * 64;
    if (q < NCLS) {
#pragma unroll
        for (int kk = 0; kk < 8; ++kk) {
            int k0 = kbase + kk * 8;
            uint4 ua = *(uint4*)&hs[w][k0];          // broadcast within grp
            uint4 ub = *(uint4*)&Ws[q * WST + k0];   // contiguous b128 row
            DOT2(yacc, ua.x, ub.x);
            DOT2(yacc, ua.y, ub.y);
            DOT2(yacc, ua.z, ub.z);
            DOT2(yacc, ua.w, ub.w);
        }
    }
    yacc += __shfl_down(yacc, 32);       // lane j<19 now has full dot
    if (lane < NCLS)
        ys[(long)node * 32 + lane] = __float2half(yacc * di);
    // cols 19..31 left as garbage: pool kernel's c0<NCLS guards discard them
}

// ---------------- layer-3 agg + pool (LDS per-graph partials) + head ----------------
// 1024 threads = 16 nodes/block. batch sorted => block spans few graph ids;
// partials staged in pg[32][24] (LDS atomics), flushed with ~span*19 global
// atomics per block. slot>=32 falls back to direct global atomics (hard guard).

__global__ __launch_bounds__(1024) void agg24h_pool_kernel(
        const __half* __restrict__ ys, const int2* __restrict__ begend,
        const unsigned short* __restrict__ csr16, const float* __restrict__ dinv,
        const int* __restrict__ batch, float* __restrict__ pool, int n) {
    __shared__ float pg[32 * 24];
    __shared__ int g0s;
    int tid = threadIdx.x;
    long nbase = (long)blockIdx.x * 16;      // first node of block
    if (tid == 0) g0s = batch[nbase < n ? nbase : (n - 1)];
    if (tid < 32 * 24) pg[tid] = 0.f;
    __syncthreads();
    int g0 = g0s;
    int node = (int)(nbase + (tid >> 6));
    int lane = tid & 63;
    bool active = node < n;
    int grp = lane >> 4, f = lane & 15;
    float2 acc = {0.f, 0.f};
    if (active) {
        float sc = dinv[node];
        int2 be = begend[node];
        int beg = be.x, end = be.y;
        int deg = end - beg;
        // whole adjacency list in registers: one coalesced 128B read per wave
        int idxv = (lane < deg) ? (int)csr16[beg + lane] : 0;
        int lim = (deg > 64) ? beg + 64 : end;
        int eb = beg;
        for (; eb + 32 <= lim; eb += 32) {       // wave-uniform trip: shfl safe
            int off = eb - beg;
            int s[8]; unsigned int u[8];
#pragma unroll
            for (int j = 0; j < 8; ++j) s[j] = __shfl(idxv, off + grp + 4 * j);
#pragma unroll
            for (int j = 0; j < 8; ++j) u[j] = ((const unsigned int*)ys)[(long)s[j] * 16 + f];
#pragma unroll
            for (int j = 0; j < 8; ++j) MIXFMA2(acc.x, acc.y, u[j], sc);
        }
        if (eb + 16 <= lim) {                    // wave-uniform predicate: shfl safe
            int off = eb - beg;
            int s[4]; unsigned int u[4];
#pragma unroll
            for (int j = 0; j < 4; ++j) s[j] = __shfl(idxv, off + grp + 4 * j);
#pragma unroll
            for (int j = 0; j < 4; ++j) u[j] = ((const unsigned int*)ys)[(long)s[j] * 16 + f];
#pragma unroll
            for (int j = 0; j < 4; ++j) MIXFMA2(acc.x, acc.y, u[j], sc);
            eb += 16;
        }
        // remainder (<16): UNIFORM exec within wave — all lanes shfl, gather predicated
#pragma unroll
        for (int r = 0; r < 4; ++r) {
            int e = eb + grp + 4 * r;
            int s = __shfl(idxv, (e - beg) & 63);
            if (e < lim) {
                unsigned int u = ((const unsigned int*)ys)[(long)s * 16 + f];
                MIXFMA2(acc.x, acc.y, u, sc);
            }
        }
        for (int e = lim + grp; e < end; e += 4) {  // deg>64 fallback: direct loads
            unsigned int u = ((const unsigned int*)ys)[(long)csr16[e] * 16 + f];
            MIXFMA2(acc.x, acc.y, u, sc);
        }
        acc.x += __shfl_down(acc.x, 32);
        acc.y += __shfl_down(acc.y, 32);
        acc.x += __shfl_down(acc.x, 16);
        acc.y += __shfl_down(acc.y, 16);
        if (lane < 16) {
            int g = batch[node];
            int slot = g - g0;                   // >=0: batch sorted
            int c0 = 2 * f;
            if (slot < 32) {                     // LDS partial (common case)
                if (c0 < NCLS) atomicAdd(&pg[slot * 24 + c0], acc.x);
                if (c0 + 1 < NCLS) atomicAdd(&pg[slot * 24 + c0 + 1], acc.y);
            } else {                             // hard-guarded fallback
                if (c0 < NCLS) atomicAdd(&pool[(long)g * 24 + c0], acc.x);
                if (c0 + 1 < NCLS) atomicAdd(&pool[(long)g * 24 + c0 + 1], acc.y);
            }
        }
    }
    __syncthreads();                             // uniform: all threads arrive
    if (tid < 32 * 24) {
        float v = pg[tid];
        if (v != 0.f) {                          // skip empty slots/cols
            int slot = tid / 24, c = tid - slot * 24;
            atomicAdd(&pool[(long)(g0 + slot) * 24 + c], v);
        }
    }
}

__global__ void final_kernel(const float* __restrict__ pool, const float* __restrict__ cnt,
                             const float* __restrict__ b3l, const float* __restrict__ bl,
                             float* __restrict__ out, int G) {
    int i = blockIdx.x * blockDim.x + threadIdx.x;
    if (i >= G * NCLS) return;
    int g = i / NCLS, j = i % NCLS;
    float c = cnt[g];
    out[i] = (c > 0.f) ? pool[(long)g * 24 + j] / c + b3l[j] + bl[j] : bl[j];
}

// ---------------- launch ----------------

static inline size_t align256(size_t x) { return (x + 255) & ~(size_t)255; }

extern "C" void kernel_launch(void* const* d_in, const int* in_sizes, int n_in,
                              void* d_out, int out_size, void* d_ws, size_t ws_size,
                              hipStream_t stream) {
    const float* x    = (const float*)d_in[0];
    const int*   ei   = (const int*)d_in[1];
    const int*   batch= (const int*)d_in[2];
    const float* W1   = (const float*)d_in[3];
    const float* b1   = (const float*)d_in[4];
    const float* W2   = (const float*)d_in[5];
    const float* b2   = (const float*)d_in[6];
    const float* W3   = (const float*)d_in[7];
    const float* b3   = (const float*)d_in[8];
    const float* Wl   = (const float*)d_in[9];
    const float* bl   = (const float*)d_in[10];
    float* out = (float*)d_out;

    const int N = in_sizes[0] / F_IN;
    const int E = in_sizes[1] / 2;
    const int G = out_size / NCLS;
    const int* src = ei;
    const int* dst = ei + E;
    const int nSB = (E + EPB - 1) / EPB;
    const int nBK = (N + RNODES - 1) / RNODES;
    // cap: mean edges per USED bucket = E*RNODES/N; +768 (~12 sigma) slack
    int cap = (int)((long long)E * RNODES / N) + 768;
    if (cap + RNODES > OUTL_CAP) cap = OUTL_CAP - RNODES;
    const int rst = cap + RNODES;

    // workspace carve-up
    char* p = (char*)d_ws;
    size_t off = 0;
    unsigned int*   bents  = (unsigned int*)(p + off);   off = align256(off + (size_t)NB * cap * 4);
    unsigned short* csr16  = (unsigned short*)(p + off); off = align256(off + (size_t)NB * rst * 2);
    int2*           begend = (int2*)(p + off);           off = align256(off + (size_t)N * 8);
    float*          dinv   = (float*)(p + off);          off = align256(off + (size_t)N * 4);
    __half*         x16h   = (__half*)(p + off);         off = align256(off + (size_t)N * 16 * 2);
    __half*         h1h    = (__half*)(p + off);         off = align256(off + (size_t)N * HIDDEN * 2);
    __half*         hsh    = (__half*)(p + off);         off = align256(off + (size_t)N * HIDDEN * 2);
    __half*         y32h   = (__half*)(p + off);         off = align256(off + (size_t)N * 32 * 2);
    __half*         W2Th   = (__half*)(p + off);         off = align256(off + (size_t)HIDDEN * HIDDEN * 2);
    __half*         W3lTh  = (__half*)(p + off);         off = align256(off + (size_t)32 * WST * 2);
    float*          b3l    = (float*)(p + off);          off = align256(off + (size_t)NCLS * 4);
    float*          pool   = (float*)(p + off);
    float*          gcnt   = pool + (size_t)G * 24;
    int*            bcur   = (int*)(pool + (size_t)G * 25);  // adjacent: one memset covers all
    off = align256(off + (size_t)G * 25 * 4 + NB * 4);
    (void)ws_size; (void)n_in;

    // one memset zeroes pool, gcnt, and bcur
    hipMemsetAsync(pool, 0, (size_t)G * 25 * 4 + NB * 4, stream);

    // CSR build (scatter includes w3lT + W2 fp16 conversion as extra blocks)
    scatter_kernel<<<nSB + 7, 1024, 0, stream>>>(src, dst, bcur, bents, E, cap, nSB,
                                                 W3, Wl, b3, W3lTh, b3l, W2, W2Th);
    build_kernel<<<nBK, 1024, 0, stream>>>(bents, bcur, x, batch, begend, csr16,
                                           dinv, gcnt, x16h, N, cap, rst);

    const int aggBlocks16 = (N + 15) / 16;  // 16 waves/block, wave per node

    // layer 1 fused: h1 = relu((sum x16h*di)@W1 + b1) -> fp16
    agg16_gemm_kernel<<<aggBlocks16, 1024, 0, stream>>>(x16h, begend, csr16, dinv, W1, b1, h1h, N);

    // layer 2: hsh = half((h1@W2)*dinv) row-major [MFMA]
    gemm_mfma_kernel<<<(N + 63) / 64, 256, 0, stream>>>(h1h, W2Th, dinv, hsh, N);

    // layer-2 agg + folded layer-3 GEMM fused: ys = ((relu(sum hsh*di + b2)) @ W3l)*di
    agg128h_y_kernel<<<aggBlocks16, 1024, 0, stream>>>(hsh, begend, csr16, dinv, b2, W3lTh, y32h, N);

    // layer-3 agg + pool (LDS per-graph partials), then head
    agg24h_pool_kernel<<<aggBlocks16, 1024, 0, stream>>>(y32h, begend, csr16, dinv, batch, pool, N);
    final_kernel<<<(G * NCLS + 255) / 256, 256, 0, stream>>>(pool, gcnt, b3l, bl, out, G);
}

// Round 14
// 199.089 us; speedup vs baseline: 1.2580x; 1.0131x over previous
//
#include <hip/hip_runtime.h>
#include <hip/hip_bf16.h>
#include <hip/hip_fp16.h>

// GCN2: 3x GCNConv(relu,relu,none) + global_mean_pool + linear head.
// R30: hoist per-node metadata loads (dinv/begend/csr16-index) ABOVE the
// weight-staging __syncthreads in all 3 agg kernels — their 200-900cy
// dependent-load chain now overlaps staging+barrier instead of starting
// after it. Straight-line hoists (clamped node), barriers stay uniform.
// R29/R25 base (best measured 200.7us): bucketed 2-phase CSR build (dense
// LDS-staged writes), fused agg16+W1, MFMA f16 layer-2 GEMM, fused
// agg128h+y (fp16 dot2 epilogue, wave-local handoff), pool LDS per-graph
// partials, folded W3@Wl head.
// Failed experiments (do not retry): R26 MFMA y-epilogue (block barrier
// serializes gather waves), R27 packed-uint agg16 gather (ILP width loss),
// R28 single-pass adj build (32x write amplification).

#define HIDDEN 128
#define F_IN 11
#define NCLS 19
#define NBITS 8
#define NB 256
#define RNODES 256
#define EPB 4096
#define OUTL_CAP 5376
#define WST 136   // WsT row stride in halves (16B-aligned rows, low bank conflict)

typedef _Float16 half8 __attribute__((ext_vector_type(8)));
typedef _Float16 half2v __attribute__((ext_vector_type(2)));
typedef float floatx4 __attribute__((ext_vector_type(4)));

// acc.{x,y,z,w} += fp16{lo(UX),hi(UX),lo(UY),hi(UY)} * DV   (one inst each)
#define MIXFMA4(A, UX, UY, DV) \
    asm("v_fma_mix_f32 %0, %4, %5, %0 op_sel_hi:[1,0,0]\n\t" \
        "v_fma_mix_f32 %1, %4, %5, %1 op_sel:[1,0,0] op_sel_hi:[1,0,0]\n\t" \
        "v_fma_mix_f32 %2, %6, %5, %2 op_sel_hi:[1,0,0]\n\t" \
        "v_fma_mix_f32 %3, %6, %5, %3 op_sel:[1,0,0] op_sel_hi:[1,0,0]" \
        : "+v"(A.x), "+v"(A.y), "+v"(A.z), "+v"(A.w) \
        : "v"(UX), "v"(DV), "v"(UY))

#define MIXFMA2(AX, AY, UU, DV) \
    asm("v_fma_mix_f32 %0, %2, %3, %0 op_sel_hi:[1,0,0]\n\t" \
        "v_fma_mix_f32 %1, %2, %3, %1 op_sel:[1,0,0] op_sel_hi:[1,0,0]" \
        : "+v"(AX), "+v"(AY) : "v"(UU), "v"(DV))

#define MIXFMA1(AX, HU, DV) \
    asm("v_fma_mix_f32 %0, %1, %2, %0 op_sel_hi:[1,0,0]" \
        : "+v"(AX) : "v"(HU), "v"(DV))

#define DOT2(ACC, UA, UB) \
    ACC = __builtin_amdgcn_fdot2(__builtin_bit_cast(half2v, UA), \
                                 __builtin_bit_cast(half2v, UB), ACC, false)

// ---------------- scatter (+ folded w3lT / W2 conversion blocks), 1024 thr ----------------

__global__ __launch_bounds__(1024) void scatter_kernel(
        const int* __restrict__ src, const int* __restrict__ dst,
        int* __restrict__ bcur, unsigned int* __restrict__ bents,
        int E, int cap, int nSB,
        const float* __restrict__ W3, const float* __restrict__ Wl,
        const float* __restrict__ b3, __half* __restrict__ W3lTh,
        float* __restrict__ b3l, const float* __restrict__ W2,
        __half* __restrict__ W2Th) {
    __shared__ int hist[NB];
    __shared__ int binoff[NB];
    __shared__ int runrel[NB];
    __shared__ unsigned int ebuf[EPB];
    __shared__ unsigned short binOf[EPB];
    __shared__ int cw[4];
    int tid = threadIdx.x, lane = tid & 63, w = tid >> 6;

    if (blockIdx.x >= nSB) {                 // ---- folded precompute blocks ----
        int xb = blockIdx.x - nSB;
        if (xb < 3) {                        // W3lT fp16 transposed (+ b3l in xb==2)
            float* Wls = (float*)ebuf;       // alias: 128*19 floats = 9.7KB
            for (int i = tid; i < HIDDEN * NCLS; i += 1024) Wls[i] = Wl[i];
            __syncthreads();
            int o = xb * 1024 + tid;
            if (o < HIDDEN * NCLS) {
                int i = o / NCLS, j = o % NCLS;
                float acc = 0.f;
#pragma unroll 8
                for (int k = 0; k < HIDDEN; ++k) acc += W3[i * HIDDEN + k] * Wls[k * NCLS + j];
                W3lTh[j * WST + i] = __float2half(acc);   // transposed fp16
            }
            if (xb == 2 && tid >= 1000 && tid < 1000 + NCLS) {
                int j = tid - 1000;
                float acc = 0.f;
#pragma unroll 8
                for (int k = 0; k < HIDDEN; ++k) acc += b3[k] * Wls[k * NCLS + j];
                b3l[j] = acc;
            }
        } else {                              // xb 3..6: W2Th[n][k] = fp16(W2[k][n])
            int base = (xb - 3) * 4096;
#pragma unroll
            for (int r = 0; r < 4; ++r) {
                int idx = base + tid + 1024 * r;
                int k = idx >> 7, nn2 = idx & 127;
                W2Th[nn2 * HIDDEN + k] = __float2half(W2[idx]);
            }
        }
        return;
    }

    // ---- scatter proper (4 edges/thread) ----
    int base = blockIdx.x * EPB;
    int cnt = min(EPB, E - base);
    if (tid < NB) hist[tid] = 0;
    __syncthreads();
    unsigned int pk[4];
    int rk[4];
#pragma unroll
    for (int j = 0; j < 4; ++j) {
        int idx = tid + 1024 * j;
        if (idx < cnt) {
            int e = base + idx;
            int s = src[e], d = dst[e];
            pk[j] = (unsigned int)s | ((unsigned int)d << 16);
            int bin = d >> NBITS;
            int r = atomicAdd(&hist[bin], 1);
            rk[j] = r | (bin << 16);
        } else rk[j] = -1;
    }
    __syncthreads();
    if (tid < NB) {                            // first 4 waves scan 256 bins
        int v = hist[tid], xv = v;
#pragma unroll
        for (int d = 1; d < 64; d <<= 1) {
            int t = __shfl_up(xv, d, 64);
            if (lane >= d) xv += t;
        }
        if (lane == 63) cw[w] = xv;
        binoff[tid] = xv - v;                  // exclusive within wave (temp)
        runrel[tid] = v ? atomicAdd(&bcur[tid], v) : 0;
    }
    __syncthreads();                           // cw[] visible to all
    if (tid < NB) {
        int waveoff = 0;
        for (int wi = 0; wi < w; ++wi) waveoff += cw[wi];
        binoff[tid] += waveoff;
    }
    __syncthreads();
#pragma unroll
    for (int j = 0; j < 4; ++j) {
        if (rk[j] >= 0) {
            int bin = rk[j] >> 16, r = rk[j] & 0xFFFF;
            int pos = binoff[bin] + r;
            ebuf[pos] = pk[j];
            binOf[pos] = (unsigned short)bin;
        }
    }
    __syncthreads();
    for (int i = tid; i < cnt; i += 1024) {
        int bin = binOf[i];
        int rel = runrel[bin] + (i - binoff[bin]);
        if (rel < cap)                          // hard guard: never cross regions
            bents[bin * cap + rel] = ebuf[i];
    }
}

// per bucket (256 nodes): counts -> scan -> LDS scatter -> dense writes. 1024 threads.
__global__ __launch_bounds__(1024) void build_kernel(
        const unsigned int* __restrict__ bents, const int* __restrict__ bcur,
        const float* __restrict__ x, const int* __restrict__ batch,
        int2* __restrict__ begend, unsigned short* __restrict__ csr16,
        float* __restrict__ dinv, float* __restrict__ gcnt,
        __half* __restrict__ x16h, int n, int cap, int rst) {
    __shared__ int counts[RNODES];
    __shared__ int lcur[RNODES];
    __shared__ unsigned short outl[OUTL_CAP];
    __shared__ int wsums[4];
    int tid = threadIdx.x;          // 1024
    int lane = tid & 63, w = tid >> 6;
    int b = blockIdx.x;
    int base = b << NBITS;
    int nn = min(RNODES, n - base);
    int ebase = b * cap;
    int ecnt = min(bcur[b], cap);   // hard guard
    int st = b * rst;
    if (tid < RNODES) counts[tid] = 0;
    __syncthreads();
    for (int e = tid; e < ecnt; e += 1024)
        atomicAdd(&counts[(bents[ebase + e] >> 16) - base], 1);
    __syncthreads();
    int v = 0, xv = 0;
    if (tid < RNODES) {             // first 4 waves scan 256 entries
        v = (tid < nn) ? counts[tid] + 1 : 0;
        xv = v;
#pragma unroll
        for (int d = 1; d < 64; d <<= 1) {
            int t = __shfl_up(xv, d, 64);
            if (lane >= d) xv += t;
        }
        if (lane == 63) wsums[w] = xv;
    }
    __syncthreads();
    if (tid < nn) {
        int waveoff = 0;
        for (int wi = 0; wi < w; ++wi) waveoff += wsums[wi];
        int excl = waveoff + xv - v;
        lcur[tid] = excl + 1;
        outl[excl] = (unsigned short)(base + tid);        // self-loop slot 0
        begend[base + tid] = make_int2(st + excl, st + excl + v);
        atomicAdd(&gcnt[batch[base + tid]], 1.0f);
    }
    __syncthreads();
    for (int e = tid; e < ecnt; e += 1024) {
        unsigned int pk = bents[ebase + e];
        int i = (int)(pk >> 16) - base;
        int r = atomicAdd(&lcur[i], 1);
        outl[r] = (unsigned short)(pk & 0xFFFFu);
    }
    __syncthreads();
    int total = ecnt + nn;
    for (int i = tid; i < total; i += 1024)
        csr16[st + i] = outl[i];
    for (int idx = tid; idx < nn * 16; idx += 1024) {
        int i = idx >> 4, j = idx & 15;
        float di = 1.0f / sqrtf((float)(counts[i] + 1));
        if (j == 0) dinv[base + i] = di;
        float xv2 = (j < F_IN) ? x[(long)(base + i) * F_IN + j] * di : 0.f;
        x16h[(long)(base + i) * 16 + j] = __float2half(xv2);
    }
}

// ---------------- layer 1 fused: agg(x16h) + GEMM W1 + relu -> h1 fp16 ----------------
// 1024 threads = 16 nodes/block. Node metadata loads hoisted above barrier.

__global__ __launch_bounds__(1024) void agg16_gemm_kernel(
        const __half* __restrict__ x16h, const int2* __restrict__ begend,
        const unsigned short* __restrict__ csr16,
        const float* __restrict__ dinv, const float* __restrict__ W1,
        const float* __restrict__ b1, __half* __restrict__ h1h, int n) {
    __shared__ float2 W1s[F_IN][64];
    __shared__ float2 bs[64];
    int tid = threadIdx.x;
    int node = (int)(((long)blockIdx.x * blockDim.x + tid) >> 6);
    int lane = tid & 63;
    int nc = (node < n) ? node : (n - 1);    // clamp: safe pre-barrier loads
    // hoisted dependent-load chain: overlaps staging + barrier below
    float di = dinv[nc];
    int2 be = begend[nc];
    int beg = be.x, end = be.y;
    int deg = end - beg;
    int idxv = (lane < deg) ? (int)csr16[beg + lane] : 0;
    // stage W1 (F_IN*64 float2 = 704) with float4: 352 float4 over 1024 threads
    if (tid < 352) ((float4*)W1s)[tid] = ((const float4*)W1)[tid];
    if (tid >= 960) bs[tid - 960] = make_float2(b1[2 * (tid - 960)], b1[2 * (tid - 960) + 1]);
    __syncthreads();
    if (node >= n) return;
    int grp = lane >> 4, f = lane & 15;
    int lim = (deg > 64) ? beg + 64 : end;
    const unsigned short* x16u = (const unsigned short*)x16h;
    float acc = 0.f;
    int eb = beg;
    for (; eb + 16 <= lim; eb += 16) {       // wave-uniform trip: shfl safe
        int off = eb - beg;
        int s[4]; unsigned int v[4];
#pragma unroll
        for (int j = 0; j < 4; ++j) s[j] = __shfl(idxv, off + grp + 4 * j);
#pragma unroll
        for (int j = 0; j < 4; ++j) v[j] = x16u[(long)s[j] * 16 + f];
#pragma unroll
        for (int j = 0; j < 4; ++j) MIXFMA1(acc, v[j], di);
    }
    if (eb + 8 <= lim) {                     // wave-uniform predicate: shfl safe
        int off = eb - beg;
        int s0 = __shfl(idxv, off + grp), s1 = __shfl(idxv, off + grp + 4);
        unsigned int v0 = x16u[(long)s0 * 16 + f], v1 = x16u[(long)s1 * 16 + f];
        MIXFMA1(acc, v0, di);
        MIXFMA1(acc, v1, di);
        eb += 8;
    }
    // remainder (<8): UNIFORM exec — all lanes shfl, gather predicated
#pragma unroll
    for (int r = 0; r < 2; ++r) {
        int e = eb + grp + 4 * r;
        int s = __shfl(idxv, (e - beg) & 63);   // clamp only matters when e>=lim
        if (e < lim) {
            unsigned int v = x16u[(long)s * 16 + f];
            MIXFMA1(acc, v, di);
        }
    }
    for (int e = lim + grp; e < end; e += 4) {  // deg>64 fallback: direct loads
        unsigned int v = x16u[(long)csr16[e] * 16 + f];
        MIXFMA1(acc, v, di);
    }
    acc += __shfl_down(acc, 32);
    acc += __shfl_down(acc, 16);
    float z = acc;                       // already scaled by dinv (folded per-term)
    float2 o = bs[lane];
#pragma unroll
    for (int k = 0; k < F_IN; ++k) {
        float zk = __shfl(z, k);
        float2 w = W1s[k][lane];
        o.x += zk * w.x;
        o.y += zk * w.y;
    }
    __half2 h = __floats2half2_rn(fmaxf(o.x, 0.f), fmaxf(o.y, 0.f));
    ((__half2*)h1h)[(long)node * 64 + lane] = h;
}

// ---------------- layer-2 GEMM: MFMA f16, W2Th pre-converted ----------------

__global__ __launch_bounds__(256) void gemm_mfma_kernel(
        const __half* __restrict__ h1h, const __half* __restrict__ W2Th,
        const float* __restrict__ dinv, __half* __restrict__ hsh, int n) {
    __shared__ _Float16 W2T[128 * 136];    // [n][k], stride 136
    __shared__ _Float16 outs[64 * 136];    // [node][feat], stride 136
    int tid = threadIdx.x;
    for (int i = tid; i < 128 * 16; i += 256) {
        int r = i >> 4, q = i & 15;
        *(uint4*)&W2T[r * 136 + q * 8] = ((const uint4*)W2Th)[r * 16 + q];
    }
    int base = blockIdx.x * 64;
    int lane = tid & 63, wid = tid >> 6;
    int l15 = lane & 15, quad = lane >> 4;
    int arow = base + wid * 16 + l15;
    if (arow >= n) arow = n - 1;           // clamp: safe reads, invalid rows unwritten
    const _Float16* Aptr = (const _Float16*)h1h + (size_t)arow * 128;
    floatx4 acc[8];
#pragma unroll
    for (int t = 0; t < 8; ++t) acc[t] = (floatx4){0.f, 0.f, 0.f, 0.f};
    __syncthreads();
#pragma unroll
    for (int c = 0; c < 4; ++c) {
        half8 a = *(const half8*)(Aptr + c * 32 + quad * 8);
#pragma unroll
        for (int t = 0; t < 8; ++t) {
            half8 b = *(const half8*)(&W2T[(t * 16 + l15) * 136 + c * 32 + quad * 8]);
            acc[t] = __builtin_amdgcn_mfma_f32_16x16x32_f16(a, b, acc[t], 0, 0, 0);
        }
    }
    float dv[4];
#pragma unroll
    for (int r = 0; r < 4; ++r) {
        int nd = base + wid * 16 + quad * 4 + r;
        dv[r] = dinv[(nd < n) ? nd : 0];
    }
#pragma unroll
    for (int t = 0; t < 8; ++t)
#pragma unroll
        for (int r = 0; r < 4; ++r)
            outs[(wid * 16 + quad * 4 + r) * 136 + t * 16 + l15] = (_Float16)(acc[t][r] * dv[r]);
    __syncthreads();
    for (int i = tid; i < 64 * 16; i += 256) {
        int ln = i >> 4, qq = i & 15;
        long nd = base + ln;
        if (nd < n) {
            uint4 u = *(uint4*)&outs[ln * 136 + qq * 8];
            ((uint4*)hsh)[nd * 16 + qq] = u;
        }
    }
}

// ---------------- 128-wide agg (layer 2) FUSED with folded layer-3 GEMM ----------------
// h2 = relu(sum(hsh*di) + b2) per-wave, handed off as fp16 in LDS;
// y = (h2 @ W3l)*di via v_dot2_f32_f16 against transposed fp16 WsT rows.
// Node metadata loads hoisted above the staging barrier.

__global__ __launch_bounds__(1024) void agg128h_y_kernel(
        const __half* __restrict__ hsh, const int2* __restrict__ begend,
        const unsigned short* __restrict__ csr16, const float* __restrict__ dinv,
        const float* __restrict__ bias, const __half* __restrict__ W3lTh,
        __half* __restrict__ ys, int n) {
    __shared__ _Float16 Ws[32 * WST];    // WsT[j][k] fp16, stride 136 (8704B)
    __shared__ _Float16 hs[16][HIDDEN];  // per-wave h2 handoff, fp16 (4KB)
    int tid = threadIdx.x;
    int node = (int)(((long)blockIdx.x * blockDim.x + tid) >> 6);
    int lane = tid & 63, w = tid >> 6;
    int nc = (node < n) ? node : (n - 1);    // clamp: safe pre-barrier loads
    // hoisted dependent-load chain: overlaps staging + barrier below
    float di = dinv[nc];
    int2 be = begend[nc];
    int beg = be.x, end = be.y;
    int deg = end - beg;
    int idxv = (lane < deg) ? (int)csr16[beg + lane] : 0;
    // 8704B = 544 float4 over 1024 threads
    if (tid < 544) ((float4*)Ws)[tid] = ((const float4*)W3lTh)[tid];
    __syncthreads();                     // Ws staging only
    if (node >= n) return;
    int grp = lane >> 5, q = lane & 31;
    int lim = (deg > 64) ? beg + 64 : end;
    float4 acc = make_float4(0.f, 0.f, 0.f, 0.f);
    int eb = beg;
    for (; eb + 16 <= lim; eb += 16) {       // wave-uniform trip: shfl safe
        int off = eb - beg;
        int s[8]; uint2 u[8];
#pragma unroll
        for (int j = 0; j < 8; ++j) s[j] = __shfl(idxv, off + grp + 2 * j);
#pragma unroll
        for (int j = 0; j < 8; ++j) u[j] = ((const uint2*)hsh)[(long)s[j] * 32 + q];
#pragma unroll
        for (int j = 0; j < 8; ++j) MIXFMA4(acc, u[j].x, u[j].y, di);
    }
    if (eb + 8 <= lim) {                     // wave-uniform predicate: shfl safe
        int s[4]; uint2 u[4];
        int off = eb - beg;
#pragma unroll
        for (int j = 0; j < 4; ++j) s[j] = __shfl(idxv, off + grp + 2 * j);
#pragma unroll
        for (int j = 0; j < 4; ++j) u[j] = ((const uint2*)hsh)[(long)s[j] * 32 + q];
#pragma unroll
        for (int j = 0; j < 4; ++j) MIXFMA4(acc, u[j].x, u[j].y, di);
        eb += 8;
    }
    // remainder (<8): UNIFORM exec — all lanes shfl, gather predicated
#pragma unroll
    for (int r = 0; r < 4; ++r) {
        int e = eb + grp + 2 * r;
        int s = __shfl(idxv, (e - beg) & 63);
        if (e < lim) {
            uint2 u = ((const uint2*)hsh)[(long)s * 32 + q];
            MIXFMA4(acc, u.x, u.y, di);
        }
    }
    for (int e = lim + grp; e < end; e += 2) {  // deg>64 fallback: direct loads
        uint2 u = ((const uint2*)hsh)[(long)csr16[e] * 32 + q];
        MIXFMA4(acc, u.x, u.y, di);
    }
    acc.x += __shfl_down(acc.x, 32);
    acc.y += __shfl_down(acc.y, 32);
    acc.z += __shfl_down(acc.z, 32);
    acc.w += __shfl_down(acc.w, 32);
    if (grp == 0) {                      // lanes 0..31 hold full h2 row (pre-scaled)
        float4 b = ((const float4*)bias)[q];
        __half2 p01 = __floats2half2_rn(fmaxf(acc.x + b.x, 0.f), fmaxf(acc.y + b.y, 0.f));
        __half2 p23 = __floats2half2_rn(fmaxf(acc.z + b.z, 0.f), fmaxf(acc.w + b.w, 0.f));
        uint2 hv = make_uint2(*(unsigned int*)&p01, *(unsigned int*)&p23);
        *(uint2*)&hs[w][q * 4] = hv;     // fp16 h2 handoff
    }
    asm volatile("s_waitcnt lgkmcnt(0)" ::: "memory");   // wave-local handoff
    // y_j = sum_k h2[k]*WsT[j][k]: lane j does k<64, lane j+32 does k>=64
    float yacc = 0.f;
    int kbase = grp * 64;
    if (q < NCLS) {
#pragma unroll
        for (int kk = 0; kk < 8; ++kk) {
            int k0 = kbase + kk * 8;
            uint4 ua = *(uint4*)&hs[w][k0];          // broadcast within grp
            uint4 ub = *(uint4*)&Ws[q * WST + k0];   // contiguous b128 row
            DOT2(yacc, ua.x, ub.x);
            DOT2(yacc, ua.y, ub.y);
            DOT2(yacc, ua.z, ub.z);
            DOT2(yacc, ua.w, ub.w);
        }
    }
    yacc += __shfl_down(yacc, 32);       // lane j<19 now has full dot
    if (lane < NCLS)
        ys[(long)node * 32 + lane] = __float2half(yacc * di);
    // cols 19..31 left as garbage: pool kernel's c0<NCLS guards discard them
}

// ---------------- layer-3 agg + pool (LDS per-graph partials) + head ----------------
// 1024 threads = 16 nodes/block. Node metadata loads hoisted above barrier.

__global__ __launch_bounds__(1024) void agg24h_pool_kernel(
        const __half* __restrict__ ys, const int2* __restrict__ begend,
        const unsigned short* __restrict__ csr16, const float* __restrict__ dinv,
        const int* __restrict__ batch, float* __restrict__ pool, int n) {
    __shared__ float pg[32 * 24];
    __shared__ int g0s;
    int tid = threadIdx.x;
    long nbase = (long)blockIdx.x * 16;      // first node of block
    int node = (int)(nbase + (tid >> 6));
    int lane = tid & 63;
    bool active = node < n;
    int nc = active ? node : (n - 1);        // clamp: safe pre-barrier loads
    // hoisted dependent-load chain: overlaps pg-zeroing + barrier below
    float sc = dinv[nc];
    int2 be = begend[nc];
    int beg = be.x, end = be.y;
    int deg = end - beg;
    int idxv = (lane < deg) ? (int)csr16[beg + lane] : 0;
    if (tid == 0) g0s = batch[nbase < n ? nbase : (n - 1)];
    if (tid < 32 * 24) pg[tid] = 0.f;
    __syncthreads();
    int g0 = g0s;
    int grp = lane >> 4, f = lane & 15;
    float2 acc = {0.f, 0.f};
    if (active) {
        int lim = (deg > 64) ? beg + 64 : end;
        int eb = beg;
        for (; eb + 32 <= lim; eb += 32) {       // wave-uniform trip: shfl safe
            int off = eb - beg;
            int s[8]; unsigned int u[8];
#pragma unroll
            for (int j = 0; j < 8; ++j) s[j] = __shfl(idxv, off + grp + 4 * j);
#pragma unroll
            for (int j = 0; j < 8; ++j) u[j] = ((const unsigned int*)ys)[(long)s[j] * 16 + f];
#pragma unroll
            for (int j = 0; j < 8; ++j) MIXFMA2(acc.x, acc.y, u[j], sc);
        }
        if (eb + 16 <= lim) {                    // wave-uniform predicate: shfl safe
            int off = eb - beg;
            int s[4]; unsigned int u[4];
#pragma unroll
            for (int j = 0; j < 4; ++j) s[j] = __shfl(idxv, off + grp + 4 * j);
#pragma unroll
            for (int j = 0; j < 4; ++j) u[j] = ((const unsigned int*)ys)[(long)s[j] * 16 + f];
#pragma unroll
            for (int j = 0; j < 4; ++j) MIXFMA2(acc.x, acc.y, u[j], sc);
            eb += 16;
        }
        // remainder (<16): UNIFORM exec within wave — all lanes shfl, gather predicated
#pragma unroll
        for (int r = 0; r < 4; ++r) {
            int e = eb + grp + 4 * r;
            int s = __shfl(idxv, (e - beg) & 63);
            if (e < lim) {
                unsigned int u = ((const unsigned int*)ys)[(long)s * 16 + f];
                MIXFMA2(acc.x, acc.y, u, sc);
            }
        }
        for (int e = lim + grp; e < end; e += 4) {  // deg>64 fallback: direct loads
            unsigned int u = ((const unsigned int*)ys)[(long)csr16[e] * 16 + f];
            MIXFMA2(acc.x, acc.y, u, sc);
        }
        acc.x += __shfl_down(acc.x, 32);
        acc.y += __shfl_down(acc.y, 32);
        acc.x += __shfl_down(acc.x, 16);
        acc.y += __shfl_down(acc.y, 16);
        if (lane < 16) {
            int g = batch[node];
            int slot = g - g0;                   // >=0: batch sorted
            int c0 = 2 * f;
            if (slot < 32) {                     // LDS partial (common case)
                if (c0 < NCLS) atomicAdd(&pg[slot * 24 + c0], acc.x);
                if (c0 + 1 < NCLS) atomicAdd(&pg[slot * 24 + c0 + 1], acc.y);
            } else {                             // hard-guarded fallback
                if (c0 < NCLS) atomicAdd(&pool[(long)g * 24 + c0], acc.x);
                if (c0 + 1 < NCLS) atomicAdd(&pool[(long)g * 24 + c0 + 1], acc.y);
            }
        }
    }
    __syncthreads();                             // uniform: all threads arrive
    if (tid < 32 * 24) {
        float v = pg[tid];
        if (v != 0.f) {                          // skip empty slots/cols
            int slot = tid / 24, c = tid - slot * 24;
            atomicAdd(&pool[(long)(g0 + slot) * 24 + c], v);
        }
    }
}

__global__ void final_kernel(const float* __restrict__ pool, const float* __restrict__ cnt,
                             const float* __restrict__ b3l, const float* __restrict__ bl,
                             float* __restrict__ out, int G) {
    int i = blockIdx.x * blockDim.x + threadIdx.x;
    if (i >= G * NCLS) return;
    int g = i / NCLS, j = i % NCLS;
    float c = cnt[g];
    out[i] = (c > 0.f) ? pool[(long)g * 24 + j] / c + b3l[j] + bl[j] : bl[j];
}

// ---------------- launch ----------------

static inline size_t align256(size_t x) { return (x + 255) & ~(size_t)255; }

extern "C" void kernel_launch(void* const* d_in, const int* in_sizes, int n_in,
                              void* d_out, int out_size, void* d_ws, size_t ws_size,
                              hipStream_t stream) {
    const float* x    = (const float*)d_in[0];
    const int*   ei   = (const int*)d_in[1];
    const int*   batch= (const int*)d_in[2];
    const float* W1   = (const float*)d_in[3];
    const float* b1   = (const float*)d_in[4];
    const float* W2   = (const float*)d_in[5];
    const float* b2   = (const float*)d_in[6];
    const float* W3   = (const float*)d_in[7];
    const float* b3   = (const float*)d_in[8];
    const float* Wl   = (const float*)d_in[9];
    const float* bl   = (const float*)d_in[10];
    float* out = (float*)d_out;

    const int N = in_sizes[0] / F_IN;
    const int E = in_sizes[1] / 2;
    const int G = out_size / NCLS;
    const int* src = ei;
    const int* dst = ei + E;
    const int nSB = (E + EPB - 1) / EPB;
    const int nBK = (N + RNODES - 1) / RNODES;
    // cap: mean edges per USED bucket = E*RNODES/N; +768 (~12 sigma) slack
    int cap = (int)((long long)E * RNODES / N) + 768;
    if (cap + RNODES > OUTL_CAP) cap = OUTL_CAP - RNODES;
    const int rst = cap + RNODES;

    // workspace carve-up
    char* p = (char*)d_ws;
    size_t off = 0;
    unsigned int*   bents  = (unsigned int*)(p + off);   off = align256(off + (size_t)NB * cap * 4);
    unsigned short* csr16  = (unsigned short*)(p + off); off = align256(off + (size_t)NB * rst * 2);
    int2*           begend = (int2*)(p + off);           off = align256(off + (size_t)N * 8);
    float*          dinv   = (float*)(p + off);          off = align256(off + (size_t)N * 4);
    __half*         x16h   = (__half*)(p + off);         off = align256(off + (size_t)N * 16 * 2);
    __half*         h1h    = (__half*)(p + off);         off = align256(off + (size_t)N * HIDDEN * 2);
    __half*         hsh    = (__half*)(p + off);         off = align256(off + (size_t)N * HIDDEN * 2);
    __half*         y32h   = (__half*)(p + off);         off = align256(off + (size_t)N * 32 * 2);
    __half*         W2Th   = (__half*)(p + off);         off = align256(off + (size_t)HIDDEN * HIDDEN * 2);
    __half*         W3lTh  = (__half*)(p + off);         off = align256(off + (size_t)32 * WST * 2);
    float*          b3l    = (float*)(p + off);          off = align256(off + (size_t)NCLS * 4);
    float*          pool   = (float*)(p + off);
    float*          gcnt   = pool + (size_t)G * 24;
    int*            bcur   = (int*)(pool + (size_t)G * 25);  // adjacent: one memset covers all
    off = align256(off + (size_t)G * 25 * 4 + NB * 4);
    (void)ws_size; (void)n_in;

    // one memset zeroes pool, gcnt, and bcur
    hipMemsetAsync(pool, 0, (size_t)G * 25 * 4 + NB * 4, stream);

    // CSR build (scatter includes w3lT + W2 fp16 conversion as extra blocks)
    scatter_kernel<<<nSB + 7, 1024, 0, stream>>>(src, dst, bcur, bents, E, cap, nSB,
                                                 W3, Wl, b3, W3lTh, b3l, W2, W2Th);
    build_kernel<<<nBK, 1024, 0, stream>>>(bents, bcur, x, batch, begend, csr16,
                                           dinv, gcnt, x16h, N, cap, rst);

    const int aggBlocks16 = (N + 15) / 16;  // 16 waves/block, wave per node

    // layer 1 fused: h1 = relu((sum x16h*di)@W1 + b1) -> fp16
    agg16_gemm_kernel<<<aggBlocks16, 1024, 0, stream>>>(x16h, begend, csr16, dinv, W1, b1, h1h, N);

    // layer 2: hsh = half((h1@W2)*dinv) row-major [MFMA]
    gemm_mfma_kernel<<<(N + 63) / 64, 256, 0, stream>>>(h1h, W2Th, dinv, hsh, N);

    // layer-2 agg + folded layer-3 GEMM fused: ys = ((relu(sum hsh*di + b2)) @ W3l)*di
    agg128h_y_kernel<<<aggBlocks16, 1024, 0, stream>>>(hsh, begend, csr16, dinv, b2, W3lTh, y32h, N);

    // layer-3 agg + pool (LDS per-graph partials), then head
    agg24h_pool_kernel<<<aggBlocks16, 1024, 0, stream>>>(y32h, begend, csr16, dinv, batch, pool, N);
    final_kernel<<<(G * NCLS + 255) / 256, 256, 0, stream>>>(pool, gcnt, b3l, bl, out, G);
}